// Round 13
// baseline (256.783 us; speedup 1.0000x reference)
//
#include <hip/hip_runtime.h>
#include <stdint.h>

typedef unsigned short u16;
typedef __attribute__((ext_vector_type(8))) unsigned short u16x8;
typedef __attribute__((ext_vector_type(8))) __bf16 bf16x8;
typedef __attribute__((ext_vector_type(4))) float f32x4;
typedef __attribute__((ext_vector_type(8))) float f32x8;

#define AS_G __attribute__((address_space(1)))
#define AS_L __attribute__((address_space(3)))

static __device__ __forceinline__ void gload_lds16(const u16* g, u16* l) {
  __builtin_amdgcn_global_load_lds((AS_G void*)(u16*)g, (AS_L void*)l, 16, 0, 0);
}

static __device__ __forceinline__ u16 f2bf(float f) {
  union { float f; unsigned u; } v; v.f = f;
  return (u16)((v.u + 0x7FFFu + ((v.u >> 16) & 1u)) >> 16);
}
static __device__ __forceinline__ float bf2f(u16 b) {
  union { unsigned u; float f; } v; v.u = ((unsigned)b) << 16;
  return v.f;
}
static __device__ __forceinline__ u16 f2bf_trunc(float f) {
  union { float f; unsigned u; } v; v.f = f;
  return (u16)(v.u >> 16);
}

#define BAR() do { asm volatile("" ::: "memory"); __builtin_amdgcn_s_barrier(); asm volatile("" ::: "memory"); } while (0)

// ---------------------------------------------------------------- cast fp32->bf16
__global__ __launch_bounds__(256) void cast_all(
    const float* __restrict__ x, const float* __restrict__ Wq,
    const float* __restrict__ Wk, const float* __restrict__ Wv,
    const float* __restrict__ Wo,
    u16* __restrict__ xb, u16* __restrict__ Wcat, u16* __restrict__ Wob)
{
  const int NX = (4096 * 2048) / 8;
  const int NW = (2048 * 2048) / 8;
  const int total = NX + 4 * NW;
  for (int i = blockIdx.x * 256 + threadIdx.x; i < total; i += gridDim.x * 256) {
    const float* src; u16* dst; int idx;
    if (i < NX)               { src = x;  dst = xb;                 idx = i; }
    else if (i < NX + NW)     { src = Wq; dst = Wcat;               idx = i - NX; }
    else if (i < NX + 2*NW)   { src = Wk; dst = Wcat + 2048*2048;   idx = i - NX - NW; }
    else if (i < NX + 3*NW)   { src = Wv; dst = Wcat + 2*2048*2048; idx = i - NX - 2*NW; }
    else                      { src = Wo; dst = Wob;                idx = i - NX - 3*NW; }
    f32x8 v = *(const f32x8*)(src + (size_t)idx * 8);
    u16x8 o;
    #pragma unroll
    for (int e = 0; e < 8; e++) o[e] = f2bf(v[e]);
    *(u16x8*)(dst + (size_t)idx * 8) = o;
  }
}

// ---------------------------------------------------------------- QKV GEMM: 256^2 dual-barrier 8-phase
// Identical to R12 EXCEPT: sched_barrier(0) removed (m141: order-pinning cost
// ~42% there; rule #18 requires it only for inline-asm ds_read — ours are
// compiler-generated, compiler tracks the deps).
__global__ __launch_bounds__(512, 2) void gemm_qkv(
    const u16* __restrict__ A, const u16* __restrict__ B,
    u16* __restrict__ QK, u16* __restrict__ Vt, int K)
{
  __shared__ char SM[131072];
  u16* Asb = (u16*)SM;               // [2][256*64] u16 = 64 KB
  u16* Bsb = (u16*)(SM + 65536);     // [2][256*64] u16 = 64 KB
  const int tid = threadIdx.x, lane = tid & 63, wid = tid >> 6;
  const int wm = wid >> 2, wn = wid & 3;
  const int row0 = blockIdx.x * 256, col0 = blockIdx.y * 256;
  const int NT = K >> 6;   // 32

  const int sr  = tid >> 3;
  const int scb = ((tid & 7) * 16) ^ ((sr & 7) << 4);

  auto stA = [&](int buf, int t, int u) {
    const u16* src = A + (size_t)(row0 + u * 64 + sr) * K + t * 64 + (scb >> 1);
    gload_lds16(src, Asb + buf * 16384 + u * 4096 + wid * 512);
  };
  auto stB = [&](int buf, int t, int u) {
    const u16* src = B + (size_t)(col0 + u * 64 + sr) * K + t * 64 + (scb >> 1);
    gload_lds16(src, Bsb + buf * 16384 + u * 4096 + wid * 512);
  };
  auto ldA = [&](int buf, int mf, int k) {
    int ra = wm * 128 + mf * 16 + (lane & 15);
    int bc = (k * 64 + ((lane >> 4) << 4)) ^ ((ra & 7) << 4);
    return *(const bf16x8*)((const char*)Asb + buf * 32768 + ra * 128 + bc);
  };
  auto ldB = [&](int buf, int nf, int k) {
    int rb = wn * 64 + nf * 16 + (lane & 15);
    int bc = (k * 64 + ((lane >> 4) << 4)) ^ ((rb & 7) << 4);
    return *(const bf16x8*)((const char*)Bsb + buf * 32768 + rb * 128 + bc);
  };

  f32x4 acc[8][4] = {};
  bf16x8 breg[4][2];

#define PH(cb, q, STAGE, DOVM) \
  { bf16x8 a0 = ldA(cb, 2*(q), 0),   a1 = ldA(cb, 2*(q), 1); \
    bf16x8 a2 = ldA(cb, 2*(q)+1, 0), a3 = ldA(cb, 2*(q)+1, 1); \
    STAGE; \
    BAR(); \
    asm volatile("s_waitcnt lgkmcnt(0)" ::: "memory"); \
    __builtin_amdgcn_s_setprio(1); \
    _Pragma("unroll") \
    for (int nf = 0; nf < 4; ++nf) { \
      acc[2*(q)][nf]   = __builtin_amdgcn_mfma_f32_16x16x32_bf16(a0, breg[nf][0], acc[2*(q)][nf], 0, 0, 0); \
      acc[2*(q)][nf]   = __builtin_amdgcn_mfma_f32_16x16x32_bf16(a1, breg[nf][1], acc[2*(q)][nf], 0, 0, 0); \
      acc[2*(q)+1][nf] = __builtin_amdgcn_mfma_f32_16x16x32_bf16(a2, breg[nf][0], acc[2*(q)+1][nf], 0, 0, 0); \
      acc[2*(q)+1][nf] = __builtin_amdgcn_mfma_f32_16x16x32_bf16(a3, breg[nf][1], acc[2*(q)+1][nf], 0, 0, 0); \
    } \
    __builtin_amdgcn_s_setprio(0); \
    DOVM; \
    BAR(); }
#define VM4 asm volatile("s_waitcnt vmcnt(4)" ::: "memory")

  // prologue: A(t0),B(t0)->buf0; B(t1)->buf1
  stA(0, 0, 0); stA(0, 0, 1); stA(0, 0, 2); stA(0, 0, 3);
  stB(0, 0, 0); stB(0, 0, 1); stB(0, 0, 2); stB(0, 0, 3);
  stB(1, 1, 0); stB(1, 1, 1); stB(1, 1, 2); stB(1, 1, 3);
  asm volatile("s_waitcnt vmcnt(4)" ::: "memory");
  BAR();

  for (int i = 0; i < NT / 2; ++i) {
    const int t1 = 2 * i + 1;
    const int t2 = (2 * i + 2 < NT) ? 2 * i + 2 : NT - 1;
    const int t3 = (2 * i + 3 < NT) ? 2 * i + 3 : NT - 1;
    // ---- K-tile 2i in buf0 ----
    #pragma unroll
    for (int nf = 0; nf < 4; ++nf) { breg[nf][0] = ldB(0, nf, 0); breg[nf][1] = ldB(0, nf, 1); }
    PH(0, 0, { stA(1, t1, 0); stA(1, t1, 1); }, );        // p0
    PH(0, 1, { stA(1, t1, 2); stA(1, t1, 3); }, );        // p1
    PH(0, 2, { stB(0, t2, 0); stB(0, t2, 1); }, );        // p2
    PH(0, 3, { stB(0, t2, 2); stB(0, t2, 3); }, VM4);     // p3
    // ---- K-tile 2i+1 in buf1 ----
    #pragma unroll
    for (int nf = 0; nf < 4; ++nf) { breg[nf][0] = ldB(1, nf, 0); breg[nf][1] = ldB(1, nf, 1); }
    PH(1, 0, { stA(0, t2, 0); stA(0, t2, 1); }, );        // p4
    PH(1, 1, { stA(0, t2, 2); stA(0, t2, 3); }, );        // p5
    PH(1, 2, { stB(1, t3, 0); stB(1, t3, 1); }, );        // p6
    PH(1, 3, { stB(1, t3, 2); stB(1, t3, 3); }, VM4);     // p7
  }
#undef PH
#undef VM4
  asm volatile("s_waitcnt vmcnt(0)" ::: "memory");
  BAR();

  if (col0 < 4096) {
    // ---- fused per-head LN (+ Q scale). Head = 128 cols = wave pair (wid, wid^1).
    float* red = (float*)SM;
    #pragma unroll
    for (int mf = 0; mf < 8; ++mf) {
      #pragma unroll
      for (int e = 0; e < 4; ++e) {
        float s = acc[mf][0][e] + acc[mf][1][e] + acc[mf][2][e] + acc[mf][3][e];
        float q = acc[mf][0][e]*acc[mf][0][e] + acc[mf][1][e]*acc[mf][1][e]
                + acc[mf][2][e]*acc[mf][2][e] + acc[mf][3][e]*acc[mf][3][e];
        #pragma unroll
        for (int m = 1; m < 16; m <<= 1) { s += __shfl_xor(s, m); q += __shfl_xor(q, m); }
        if ((lane & 15) == 0) {
          int rl = mf * 16 + (lane >> 4) * 4 + e;
          red[wid * 256 + rl * 2]     = s;
          red[wid * 256 + rl * 2 + 1] = q;
        }
      }
    }
    BAR();
    const float mul = (col0 < 2048) ? (0.08838834764831845f * 1.4426950408889634f) : 1.0f;
    #pragma unroll
    for (int mf = 0; mf < 8; ++mf) {
      #pragma unroll
      for (int e = 0; e < 4; ++e) {
        int rl = mf * 16 + (lane >> 4) * 4 + e;
        float s = red[wid * 256 + rl * 2]     + red[(wid ^ 1) * 256 + rl * 2];
        float q = red[wid * 256 + rl * 2 + 1] + red[(wid ^ 1) * 256 + rl * 2 + 1];
        float mu = s * (1.f / 128.f);
        float var = q * (1.f / 128.f) - mu * mu;
        float rstd = rsqrtf(var + 1e-5f) * mul;
        int r = row0 + wm * 128 + rl;
        #pragma unroll
        for (int nf = 0; nf < 4; ++nf) {
          int c = col0 + wn * 64 + nf * 16 + (lane & 15);
          QK[(size_t)r * 4096 + c] = f2bf((acc[mf][nf][e] - mu) * rstd);
        }
      }
    }
  } else {
    // ---- V panels: in-LDS transpose, 2 passes of 128 cols -> Vt[b,h,d,l]
    u16* T = (u16*)SM;
    const int b = row0 >> 11;
    #pragma unroll
    for (int pass = 0; pass < 2; ++pass) {
      if ((wn >> 1) == pass) {
        #pragma unroll
        for (int mf = 0; mf < 8; ++mf)
          #pragma unroll
          for (int nf = 0; nf < 4; ++nf)
            #pragma unroll
            for (int e = 0; e < 4; ++e) {
              int r = wm * 128 + mf * 16 + (lane >> 4) * 4 + e;
              int c = (wn & 1) * 64 + nf * 16 + (lane & 15);
              T[c * 264 + r] = f2bf(acc[mf][nf][e]);
            }
      }
      BAR();
      {
        const int c = tid & 127, seg = tid >> 7;
        const int dg = col0 - 4096 + pass * 128 + c;
        const int h = dg >> 7, dd = dg & 127;
        u16* dst = Vt + ((size_t)((b * 16 + h) * 128 + dd)) * 2048 + (row0 & 2047) + seg * 64;
        const u16* srcT = T + c * 264 + seg * 64;
        #pragma unroll
        for (int jj = 0; jj < 8; ++jj)
          *(u16x8*)(dst + jj * 8) = *(const u16x8*)(srcT + jj * 8);
      }
      BAR();
    }
  }
}

// ---------------------------------------------------------------- AO @ Wo^T + bias (unchanged)
__global__ __launch_bounds__(512, 2) void gemm_ao(
    const u16* __restrict__ A, const u16* __restrict__ B,
    float* __restrict__ C, const float* __restrict__ bias,
    int M, int N, int K)
{
  __shared__ u16 As[2][256 * 64];
  __shared__ u16 Bs[2][128 * 64];
  const int tid = threadIdx.x, lane = tid & 63, wid = tid >> 6;
  const int wm = wid >> 1, wn = wid & 1;
  const int row0 = blockIdx.y * 256, col0 = blockIdx.x * 128;
  const int NT = K >> 6;

  const int sr  = tid >> 3;
  const int scb = ((tid & 7) * 16) ^ ((sr & 7) << 4);

  auto stA = [&](int buf, int t, int u) {
    const u16* src = A + (size_t)(row0 + u * 64 + sr) * K + t * 64 + (scb >> 1);
    gload_lds16(src, As[buf] + u * 4096 + wid * 512);
  };
  auto stB = [&](int buf, int t, int u) {
    const u16* src = B + (size_t)(col0 + u * 64 + sr) * K + t * 64 + (scb >> 1);
    gload_lds16(src, Bs[buf] + u * 4096 + wid * 512);
  };
  auto ldA = [&](int buf, int mf, int k) {
    int ra = wm * 64 + mf * 16 + (lane & 15);
    int bc = (k * 64 + ((lane >> 4) << 4)) ^ ((ra & 7) << 4);
    return *(const bf16x8*)((const char*)As[buf] + ra * 128 + bc);
  };
  auto ldB = [&](int buf, int nf, int k) {
    int rb = wn * 64 + nf * 16 + (lane & 15);
    int bc = (k * 64 + ((lane >> 4) << 4)) ^ ((rb & 7) << 4);
    return *(const bf16x8*)((const char*)Bs[buf] + rb * 128 + bc);
  };

  f32x4 acc[4][4] = {};
  bf16x8 breg[4][2];

  stA(0, 0, 0); stA(0, 0, 1); stA(0, 0, 2); stA(0, 0, 3);
  stB(0, 0, 0); stB(0, 0, 1);
  stB(1, 1, 0); stB(1, 1, 1);
  asm volatile("s_waitcnt vmcnt(2)" ::: "memory");
  BAR();

  for (int it = 0; it < NT / 2; ++it) {
    const int t1  = 2 * it + 1;
    const int pf0 = (2 * it + 2 < NT) ? (2 * it + 2) : (NT - 1);
    const int pf1 = (2 * it + 3 < NT) ? (2 * it + 3) : (NT - 1);
    #pragma unroll
    for (int hf = 0; hf < 2; ++hf) {
      const int cb = hf;
      #pragma unroll
      for (int nf = 0; nf < 4; ++nf) { breg[nf][0] = ldB(cb, nf, 0); breg[nf][1] = ldB(cb, nf, 1); }
      bf16x8 a0 = ldA(cb, 0, 0), a1 = ldA(cb, 0, 1);
      BAR();
      if (hf == 0) { stA(1, t1, 0); stA(1, t1, 1); } else { stA(0, pf0, 0); stA(0, pf0, 1); }
      __builtin_amdgcn_s_setprio(1);
      #pragma unroll
      for (int nf = 0; nf < 4; ++nf) {
        acc[0][nf] = __builtin_amdgcn_mfma_f32_16x16x32_bf16(a0, breg[nf][0], acc[0][nf], 0, 0, 0);
        acc[0][nf] = __builtin_amdgcn_mfma_f32_16x16x32_bf16(a1, breg[nf][1], acc[0][nf], 0, 0, 0);
      }
      __builtin_amdgcn_s_setprio(0);
      bf16x8 b0 = ldA(cb, 1, 0), b1 = ldA(cb, 1, 1);
      bf16x8 c0 = ldA(cb, 2, 0), c1 = ldA(cb, 2, 1);
      BAR();
      if (hf == 0) { stA(1, t1, 2); stA(1, t1, 3); } else { stA(0, pf0, 2); stA(0, pf0, 3); }
      __builtin_amdgcn_s_setprio(1);
      #pragma unroll
      for (int nf = 0; nf < 4; ++nf) {
        acc[1][nf] = __builtin_amdgcn_mfma_f32_16x16x32_bf16(b0, breg[nf][0], acc[1][nf], 0, 0, 0);
        acc[1][nf] = __builtin_amdgcn_mfma_f32_16x16x32_bf16(b1, breg[nf][1], acc[1][nf], 0, 0, 0);
        acc[2][nf] = __builtin_amdgcn_mfma_f32_16x16x32_bf16(c0, breg[nf][0], acc[2][nf], 0, 0, 0);
        acc[2][nf] = __builtin_amdgcn_mfma_f32_16x16x32_bf16(c1, breg[nf][1], acc[2][nf], 0, 0, 0);
      }
      __builtin_amdgcn_s_setprio(0);
      a0 = ldA(cb, 3, 0); a1 = ldA(cb, 3, 1);
      BAR();
      if (hf == 0) { stB(0, pf0, 0); stB(0, pf0, 1); } else { stB(1, pf1, 0); stB(1, pf1, 1); }
      __builtin_amdgcn_s_setprio(1);
      #pragma unroll
      for (int nf = 0; nf < 4; ++nf) {
        acc[3][nf] = __builtin_amdgcn_mfma_f32_16x16x32_bf16(a0, breg[nf][0], acc[3][nf], 0, 0, 0);
        acc[3][nf] = __builtin_amdgcn_mfma_f32_16x16x32_bf16(a1, breg[nf][1], acc[3][nf], 0, 0, 0);
      }
      __builtin_amdgcn_s_setprio(0);
      asm volatile("s_waitcnt vmcnt(2)" ::: "memory");
      BAR();
    }
  }
  asm volatile("s_waitcnt vmcnt(0)" ::: "memory");

  #pragma unroll
  for (int mf = 0; mf < 4; ++mf) {
    #pragma unroll
    for (int nf = 0; nf < 4; ++nf) {
      #pragma unroll
      for (int e = 0; e < 4; ++e) {
        int r = row0 + wm * 64 + mf * 16 + (lane >> 4) * 4 + e;
        int c = col0 + wn * 64 + nf * 16 + (lane & 15);
        C[(size_t)r * N + c] = acc[mf][nf][e] + bias[c];
      }
    }
  }
}

// ---------------------------------------------------------------- attn staging helpers
static __device__ __forceinline__ void stage_k_tile(
    const u16* __restrict__ QK, int b, int h, int j0, u16* Kbuf, int tid, int wid)
{
  #pragma unroll
  for (int i = 0; i < 4; i++) {
    int c = i * 256 + tid;
    int r = c >> 4, ob = (c & 15) * 16;
    int cb = ob ^ ((r & 7) << 4);
    const u16* g = QK + (size_t)(b*2048 + j0 + r) * 4096 + 2048 + h*128 + (cb >> 1);
    gload_lds16(g, Kbuf + (i * 256 + wid * 64) * 8);
  }
}
static __device__ __forceinline__ void stage_v_tile(
    const u16* __restrict__ Vt, int b, int h, int j0, u16* Vbuf, int tid, int wid)
{
  #pragma unroll
  for (int i = 0; i < 4; i++) {
    int c = i * 256 + tid;
    int r = c >> 3, ob = (c & 7) * 16;
    int cb = ob ^ ((r & 7) << 4);
    const u16* g = Vt + (size_t)((b*16 + h) * 128 + r) * 2048 + j0 + (cb >> 1);
    gload_lds16(g, Vbuf + (i * 256 + wid * 64) * 8);
  }
}

// ---------------------------------------------------------------- causal flash attention (unchanged from R11)
__global__ __launch_bounds__(256, 2) void attn(
    const u16* __restrict__ QK, const u16* __restrict__ Vt, u16* __restrict__ AO)
{
  const int flat = blockIdx.x;
  const int xcd = flat & 7;
  const int j   = flat >> 3;
  const int k   = j >> 1, odd = j & 1;
  int qt, inst;
  if (k < 16) { qt = odd ? 15 - k : k;      inst = odd ? 1 : 0; }
  else        { qt = odd ? k - 16 : 31 - k; inst = odd ? 3 : 2; }
  const int hb = xcd * 4 + inst;
  const int h = hb & 15, b = hb >> 4;
  const int tid = threadIdx.x, lane = tid & 63, wid = tid >> 6;

  __shared__ u16 Ks[2][64 * 128];
  __shared__ u16 Vs[2][128 * 64];
  __shared__ u16 Ps[4][32 * 64];

  const int l0 = qt * 128;
  const int ntile = 2 * qt + 2;

  bf16x8 qa[2][4];
  #pragma unroll
  for (int mt = 0; mt < 2; mt++) {
    const u16* qrow = QK + (size_t)(b*2048 + l0 + wid*32 + mt*16 + (lane & 15)) * 4096
                      + h*128 + (lane >> 4) * 8;
    #pragma unroll
    for (int ks = 0; ks < 4; ks++) qa[mt][ks] = *(const bf16x8*)(qrow + ks * 32);
  }

  f32x4 o[2][8] = {};
  float lrun[8];
  #pragma unroll
  for (int i = 0; i < 8; i++) lrun[i] = 0.f;

  stage_v_tile(Vt, b, h, 0, Vs[0], tid, wid);
  stage_k_tile(QK, b, h, 0, Ks[0], tid, wid);
  int cur = 0;

  for (int t = 0; t < ntile; t++) {
    const int j0 = t * 64;
    if (t + 1 < ntile) {
      stage_v_tile(Vt, b, h, (t + 1) * 64, Vs[cur ^ 1], tid, wid);
      stage_k_tile(QK, b, h, (t + 1) * 64, Ks[cur ^ 1], tid, wid);
      asm volatile("s_waitcnt vmcnt(8)" ::: "memory");
    } else {
      asm volatile("s_waitcnt vmcnt(0)" ::: "memory");
    }
    __builtin_amdgcn_s_barrier();
    asm volatile("" ::: "memory");

    const bool skip = (t == ntile - 1) && (wid < 2);
    if (!skip) {
      f32x4 s[2][4] = {};
      const char* Kc = (const char*)Ks[cur];
      __builtin_amdgcn_s_setprio(1);
      #pragma unroll
      for (int nt = 0; nt < 4; nt++) {
        #pragma unroll
        for (int ks = 0; ks < 4; ks++) {
          int r = nt * 16 + (lane & 15);
          int cb = ks * 64 + (lane >> 4) * 16;
          bf16x8 kb = *(const bf16x8*)(Kc + r * 256 + (cb ^ ((lane & 7) << 4)));
          s[0][nt] = __builtin_amdgcn_mfma_f32_16x16x32_bf16(qa[0][ks], kb, s[0][nt], 0, 0, 0);
          s[1][nt] = __builtin_amdgcn_mfma_f32_16x16x32_bf16(qa[1][ks], kb, s[1][nt], 0, 0, 0);
        }
      }
      __builtin_amdgcn_s_setprio(0);

      if (t >= ntile - 2) {
        #pragma unroll
        for (int mt = 0; mt < 2; mt++) {
          #pragma unroll
          for (int nt = 0; nt < 4; nt++) {
            #pragma unroll
            for (int e = 0; e < 4; e++) {
              int ig = l0 + wid * 32 + mt * 16 + (lane >> 4) * 4 + e;
              int jg = j0 + nt * 16 + (lane & 15);
              if (jg > ig) s[mt][nt][e] = -1e30f;
            }
          }
        }
      }

      char* PsW = (char*)Ps[wid];
      #pragma unroll
      for (int mt = 0; mt < 2; mt++) {
        #pragma unroll
        for (int nt = 0; nt < 4; nt++) {
          #pragma unroll
          for (int e = 0; e < 4; e++) {
            float p = exp2f(s[mt][nt][e]);
            lrun[mt * 4 + e] += p;
            int i_ = mt * 16 + (lane >> 4) * 4 + e;
            int jb = (nt * 16 + (lane & 15)) * 2;
            *(u16*)(PsW + i_ * 128 + (jb ^ ((i_ & 7) << 4))) = f2bf_trunc(p);
          }
        }
      }

      const char* Vc = (const char*)Vs[cur];
      __builtin_amdgcn_s_setprio(1);
      #pragma unroll
      for (int ks = 0; ks < 2; ks++) {
        int jb = ks * 64 + (lane >> 4) * 16;
        bf16x8 pa[2];
        #pragma unroll
        for (int mt = 0; mt < 2; mt++) {
          int ir = mt * 16 + (lane & 15);
          pa[mt] = *(const bf16x8*)(PsW + ir * 128 + (jb ^ ((ir & 7) << 4)));
        }
        #pragma unroll
        for (int dt = 0; dt < 8; dt++) {
          int dr = dt * 16 + (lane & 15);
          bf16x8 vb = *(const bf16x8*)(Vc + dr * 128 + (jb ^ ((lane & 7) << 4)));
          o[0][dt] = __builtin_amdgcn_mfma_f32_16x16x32_bf16(pa[0], vb, o[0][dt], 0, 0, 0);
          o[1][dt] = __builtin_amdgcn_mfma_f32_16x16x32_bf16(pa[1], vb, o[1][dt], 0, 0, 0);
        }
      }
      __builtin_amdgcn_s_setprio(0);
    }

    asm volatile("s_waitcnt lgkmcnt(0)" ::: "memory");
    __builtin_amdgcn_s_barrier();
    asm volatile("" ::: "memory");
    cur ^= 1;
  }

  #pragma unroll
  for (int mt = 0; mt < 2; mt++) {
    #pragma unroll
    for (int e = 0; e < 4; e++) {
      float l = lrun[mt * 4 + e];
      l += __shfl_xor(l, 1);
      l += __shfl_xor(l, 2);
      l += __shfl_xor(l, 4);
      l += __shfl_xor(l, 8);
      float inv = 1.0f / l;
      int rglob = b * 2048 + l0 + wid * 32 + mt * 16 + (lane >> 4) * 4 + e;
      #pragma unroll
      for (int dt = 0; dt < 8; dt++)
        AO[(size_t)rglob * 2048 + h * 128 + dt * 16 + (lane & 15)] = f2bf(o[mt][dt][e] * inv);
    }
  }
}

// ---------------------------------------------------------------- launch
extern "C" void kernel_launch(void* const* d_in, const int* in_sizes, int n_in,
                              void* d_out, int out_size, void* d_ws, size_t ws_size,
                              hipStream_t stream)
{
  const float* x  = (const float*)d_in[0];
  const float* Wq = (const float*)d_in[1];
  const float* Wk = (const float*)d_in[2];
  const float* Wv = (const float*)d_in[3];
  const float* Wo = (const float*)d_in[4];
  const float* bo = (const float*)d_in[5];

  char* ws = (char*)d_ws;
  u16* xb   = (u16*)(ws);
  u16* Wcat = (u16*)(ws + 16777216);
  u16* Wob  = (u16*)(ws + 16777216 + 25165824);
  u16* QK   = (u16*)(ws + 16777216 + 25165824 + 8388608);
  u16* Vt   = (u16*)(ws + 16777216 + 25165824 + 8388608 + 33554432);
  u16* AO   = xb;

  cast_all<<<dim3(2048), dim3(256), 0, stream>>>(x, Wq, Wk, Wv, Wo, xb, Wcat, Wob);
  gemm_qkv<<<dim3(16, 24), dim3(512), 0, stream>>>(xb, Wcat, QK, Vt, 2048);
  attn<<<dim3(512), dim3(256), 0, stream>>>(QK, Vt, AO);
  gemm_ao<<<dim3(16, 16), dim3(512), 0, stream>>>(AO, Wob, (float*)d_out, bo, 4096, 2048, 2048);
}

// Round 14
// 244.636 us; speedup vs baseline: 1.0497x; 1.0497x over previous
//
#include <hip/hip_runtime.h>
#include <stdint.h>

typedef unsigned short u16;
typedef __attribute__((ext_vector_type(4))) unsigned short u16x4;
typedef __attribute__((ext_vector_type(8))) unsigned short u16x8;
typedef __attribute__((ext_vector_type(8))) __bf16 bf16x8;
typedef __attribute__((ext_vector_type(4))) float f32x4;
typedef __attribute__((ext_vector_type(8))) float f32x8;

#define AS_G __attribute__((address_space(1)))
#define AS_L __attribute__((address_space(3)))

static __device__ __forceinline__ void gload_lds16(const u16* g, u16* l) {
  __builtin_amdgcn_global_load_lds((AS_G void*)(u16*)g, (AS_L void*)l, 16, 0, 0);
}

static __device__ __forceinline__ u16 f2bf(float f) {
  union { float f; unsigned u; } v; v.f = f;
  return (u16)((v.u + 0x7FFFu + ((v.u >> 16) & 1u)) >> 16);
}
static __device__ __forceinline__ float bf2f(u16 b) {
  union { unsigned u; float f; } v; v.u = ((unsigned)b) << 16;
  return v.f;
}
static __device__ __forceinline__ u16 f2bf_trunc(float f) {
  union { float f; unsigned u; } v; v.f = f;
  return (u16)(v.u >> 16);
}

#define BAR() do { asm volatile("" ::: "memory"); __builtin_amdgcn_s_barrier(); asm volatile("" ::: "memory"); } while (0)

// ---------------------------------------------------------------- cast fp32->bf16
__global__ __launch_bounds__(256) void cast_all(
    const float* __restrict__ x, const float* __restrict__ Wq,
    const float* __restrict__ Wk, const float* __restrict__ Wv,
    const float* __restrict__ Wo,
    u16* __restrict__ xb, u16* __restrict__ Wcat, u16* __restrict__ Wob)
{
  const int NX = (4096 * 2048) / 8;
  const int NW = (2048 * 2048) / 8;
  const int total = NX + 4 * NW;
  for (int i = blockIdx.x * 256 + threadIdx.x; i < total; i += gridDim.x * 256) {
    const float* src; u16* dst; int idx;
    if (i < NX)               { src = x;  dst = xb;                 idx = i; }
    else if (i < NX + NW)     { src = Wq; dst = Wcat;               idx = i - NX; }
    else if (i < NX + 2*NW)   { src = Wk; dst = Wcat + 2048*2048;   idx = i - NX - NW; }
    else if (i < NX + 3*NW)   { src = Wv; dst = Wcat + 2*2048*2048; idx = i - NX - 2*NW; }
    else                      { src = Wo; dst = Wob;                idx = i - NX - 3*NW; }
    f32x8 v = *(const f32x8*)(src + (size_t)idx * 8);
    u16x8 o;
    #pragma unroll
    for (int e = 0; e < 8; e++) o[e] = f2bf(v[e]);
    *(u16x8*)(dst + (size_t)idx * 8) = o;
  }
}

// ---------------------------------------------------------------- QKV GEMM (REVERTED to R11: BM=128 x BN=256, 117.7us / 877 TF)
__global__ __launch_bounds__(512, 1) void gemm_qkv(
    const u16* __restrict__ A, const u16* __restrict__ B,
    u16* __restrict__ QK, u16* __restrict__ Vt, int K)
{
  __shared__ char SM[98304];
  u16* Asb = (u16*)SM;
  u16* Bsb = (u16*)(SM + 32768);
  const int tid = threadIdx.x, lane = tid & 63, wid = tid >> 6;
  const int wm = wid >> 2, wn = wid & 3;
  const int row0 = blockIdx.x * 128, col0 = blockIdx.y * 256;
  const int NT = K >> 6;

  const int sr  = tid >> 3;
  const int scb = ((tid & 7) * 16) ^ ((sr & 7) << 4);

  auto stA = [&](int buf, int t, int u) {
    const u16* src = A + (size_t)(row0 + u * 64 + sr) * K + t * 64 + (scb >> 1);
    gload_lds16(src, Asb + buf * 8192 + u * 4096 + wid * 512);
  };
  auto stB = [&](int buf, int t, int u) {
    const u16* src = B + (size_t)(col0 + u * 64 + sr) * K + t * 64 + (scb >> 1);
    gload_lds16(src, Bsb + buf * 16384 + u * 4096 + wid * 512);
  };
  auto ldA = [&](int buf, int mf, int k) {
    int ra = wm * 64 + mf * 16 + (lane & 15);
    int bc = (k * 64 + ((lane >> 4) << 4)) ^ ((ra & 7) << 4);
    return *(const bf16x8*)((const char*)Asb + buf * 16384 + ra * 128 + bc);
  };
  auto ldB = [&](int buf, int nf, int k) {
    int rb = wn * 64 + nf * 16 + (lane & 15);
    int bc = (k * 64 + ((lane >> 4) << 4)) ^ ((rb & 7) << 4);
    return *(const bf16x8*)((const char*)Bsb + buf * 32768 + rb * 128 + bc);
  };

  f32x4 acc[4][4] = {};
  bf16x8 breg[4][2];

#define MFMA_PH(mf, x0, x1) \
  do { __builtin_amdgcn_s_setprio(1); \
    _Pragma("unroll") \
    for (int nf = 0; nf < 4; ++nf) { \
      acc[mf][nf] = __builtin_amdgcn_mfma_f32_16x16x32_bf16(x0, breg[nf][0], acc[mf][nf], 0, 0, 0); \
      acc[mf][nf] = __builtin_amdgcn_mfma_f32_16x16x32_bf16(x1, breg[nf][1], acc[mf][nf], 0, 0, 0); \
    } \
    __builtin_amdgcn_s_setprio(0); } while (0)

  stA(0, 0, 0); stA(0, 0, 1);
  stB(0, 0, 0); stB(0, 0, 1); stB(0, 0, 2); stB(0, 0, 3);
  stB(1, 1, 0); stB(1, 1, 1); stB(1, 1, 2); stB(1, 1, 3);
  asm volatile("s_waitcnt vmcnt(4)" ::: "memory");
  BAR();

  for (int it = 0; it < NT / 2; ++it) {
    const int t1  = 2 * it + 1;
    const int pf0 = (2 * it + 2 < NT) ? (2 * it + 2) : (NT - 1);
    const int pf1 = (2 * it + 3 < NT) ? (2 * it + 3) : (NT - 1);
    #pragma unroll
    for (int hf = 0; hf < 2; ++hf) {
      const int cb = hf;
      #pragma unroll
      for (int nf = 0; nf < 4; ++nf) { breg[nf][0] = ldB(cb, nf, 0); breg[nf][1] = ldB(cb, nf, 1); }
      bf16x8 a0 = ldA(cb, 0, 0), a1 = ldA(cb, 0, 1);
      BAR();
      if (hf == 0) { stA(1, t1, 0); stA(1, t1, 1); } else { stA(0, pf0, 0); stA(0, pf0, 1); }
      MFMA_PH(0, a0, a1);
      a0 = ldA(cb, 1, 0); a1 = ldA(cb, 1, 1);
      BAR();
      if (hf == 0) { stB(0, pf0, 0); stB(0, pf0, 1); } else { stB(1, pf1, 0); stB(1, pf1, 1); }
      MFMA_PH(1, a0, a1);
      a0 = ldA(cb, 2, 0); a1 = ldA(cb, 2, 1);
      BAR();
      if (hf == 0) { stB(0, pf0, 2); stB(0, pf0, 3); } else { stB(1, pf1, 2); stB(1, pf1, 3); }
      MFMA_PH(2, a0, a1);
      a0 = ldA(cb, 3, 0); a1 = ldA(cb, 3, 1);
      MFMA_PH(3, a0, a1);
      asm volatile("s_waitcnt vmcnt(4)" ::: "memory");
      BAR();
    }
  }
  asm volatile("s_waitcnt vmcnt(0)" ::: "memory");
  BAR();

  if (col0 < 4096) {
    float* red = (float*)SM;
    #pragma unroll
    for (int mf = 0; mf < 4; ++mf) {
      #pragma unroll
      for (int e = 0; e < 4; ++e) {
        float s = acc[mf][0][e] + acc[mf][1][e] + acc[mf][2][e] + acc[mf][3][e];
        float q = acc[mf][0][e]*acc[mf][0][e] + acc[mf][1][e]*acc[mf][1][e]
                + acc[mf][2][e]*acc[mf][2][e] + acc[mf][3][e]*acc[mf][3][e];
        #pragma unroll
        for (int m = 1; m < 16; m <<= 1) { s += __shfl_xor(s, m); q += __shfl_xor(q, m); }
        if ((lane & 15) == 0) {
          int rl = mf * 16 + (lane >> 4) * 4 + e;
          red[wid * 128 + rl * 2]     = s;
          red[wid * 128 + rl * 2 + 1] = q;
        }
      }
    }
    BAR();
    const float mul = (col0 < 2048) ? (0.08838834764831845f * 1.4426950408889634f) : 1.0f;
    #pragma unroll
    for (int mf = 0; mf < 4; ++mf) {
      #pragma unroll
      for (int e = 0; e < 4; ++e) {
        int rl = mf * 16 + (lane >> 4) * 4 + e;
        float s = red[wid * 128 + rl * 2]     + red[(wid ^ 1) * 128 + rl * 2];
        float q = red[wid * 128 + rl * 2 + 1] + red[(wid ^ 1) * 128 + rl * 2 + 1];
        float mu = s * (1.f / 128.f);
        float var = q * (1.f / 128.f) - mu * mu;
        float rstd = rsqrtf(var + 1e-5f) * mul;
        int r = row0 + wm * 64 + rl;
        #pragma unroll
        for (int nf = 0; nf < 4; ++nf) {
          int c = col0 + wn * 64 + nf * 16 + (lane & 15);
          QK[(size_t)r * 4096 + c] = f2bf((acc[mf][nf][e] - mu) * rstd);
        }
      }
    }
  } else {
    u16* T = (u16*)SM;
    #pragma unroll
    for (int mf = 0; mf < 4; ++mf) {
      #pragma unroll
      for (int nf = 0; nf < 4; ++nf) {
        #pragma unroll
        for (int e = 0; e < 4; ++e) {
          int r = wm * 64 + mf * 16 + (lane >> 4) * 4 + e;
          int c = wn * 64 + nf * 16 + (lane & 15);
          T[c * 136 + r] = f2bf(acc[mf][nf][e]);
        }
      }
    }
    BAR();
    const int dr = tid >> 1, half = tid & 1;
    const int dg = col0 - 4096 + dr;
    const int h = dg >> 7, dd = dg & 127;
    const int b = row0 >> 11;
    const int lb = (row0 & 2047) + half * 64;
    u16* dst = Vt + ((size_t)((b * 16 + h) * 128 + dd)) * 2048 + lb;
    const u16* srcT = T + dr * 136 + half * 64;
    #pragma unroll
    for (int j = 0; j < 8; ++j)
      *(u16x8*)(dst + j * 8) = *(const u16x8*)(srcT + j * 8);
  }
#undef MFMA_PH
}

// ---------------------------------------------------------------- AO @ Wo^T + bias (unchanged)
__global__ __launch_bounds__(512, 2) void gemm_ao(
    const u16* __restrict__ A, const u16* __restrict__ B,
    float* __restrict__ C, const float* __restrict__ bias,
    int M, int N, int K)
{
  __shared__ u16 As[2][256 * 64];
  __shared__ u16 Bs[2][128 * 64];
  const int tid = threadIdx.x, lane = tid & 63, wid = tid >> 6;
  const int wm = wid >> 1, wn = wid & 1;
  const int row0 = blockIdx.y * 256, col0 = blockIdx.x * 128;
  const int NT = K >> 6;

  const int sr  = tid >> 3;
  const int scb = ((tid & 7) * 16) ^ ((sr & 7) << 4);

  auto stA = [&](int buf, int t, int u) {
    const u16* src = A + (size_t)(row0 + u * 64 + sr) * K + t * 64 + (scb >> 1);
    gload_lds16(src, As[buf] + u * 4096 + wid * 512);
  };
  auto stB = [&](int buf, int t, int u) {
    const u16* src = B + (size_t)(col0 + u * 64 + sr) * K + t * 64 + (scb >> 1);
    gload_lds16(src, Bs[buf] + u * 4096 + wid * 512);
  };
  auto ldA = [&](int buf, int mf, int k) {
    int ra = wm * 64 + mf * 16 + (lane & 15);
    int bc = (k * 64 + ((lane >> 4) << 4)) ^ ((ra & 7) << 4);
    return *(const bf16x8*)((const char*)As[buf] + ra * 128 + bc);
  };
  auto ldB = [&](int buf, int nf, int k) {
    int rb = wn * 64 + nf * 16 + (lane & 15);
    int bc = (k * 64 + ((lane >> 4) << 4)) ^ ((rb & 7) << 4);
    return *(const bf16x8*)((const char*)Bs[buf] + rb * 128 + bc);
  };

  f32x4 acc[4][4] = {};
  bf16x8 breg[4][2];

  stA(0, 0, 0); stA(0, 0, 1); stA(0, 0, 2); stA(0, 0, 3);
  stB(0, 0, 0); stB(0, 0, 1);
  stB(1, 1, 0); stB(1, 1, 1);
  asm volatile("s_waitcnt vmcnt(2)" ::: "memory");
  BAR();

  for (int it = 0; it < NT / 2; ++it) {
    const int t1  = 2 * it + 1;
    const int pf0 = (2 * it + 2 < NT) ? (2 * it + 2) : (NT - 1);
    const int pf1 = (2 * it + 3 < NT) ? (2 * it + 3) : (NT - 1);
    #pragma unroll
    for (int hf = 0; hf < 2; ++hf) {
      const int cb = hf;
      #pragma unroll
      for (int nf = 0; nf < 4; ++nf) { breg[nf][0] = ldB(cb, nf, 0); breg[nf][1] = ldB(cb, nf, 1); }
      bf16x8 a0 = ldA(cb, 0, 0), a1 = ldA(cb, 0, 1);
      BAR();
      if (hf == 0) { stA(1, t1, 0); stA(1, t1, 1); } else { stA(0, pf0, 0); stA(0, pf0, 1); }
      __builtin_amdgcn_s_setprio(1);
      #pragma unroll
      for (int nf = 0; nf < 4; ++nf) {
        acc[0][nf] = __builtin_amdgcn_mfma_f32_16x16x32_bf16(a0, breg[nf][0], acc[0][nf], 0, 0, 0);
        acc[0][nf] = __builtin_amdgcn_mfma_f32_16x16x32_bf16(a1, breg[nf][1], acc[0][nf], 0, 0, 0);
      }
      __builtin_amdgcn_s_setprio(0);
      bf16x8 b0 = ldA(cb, 1, 0), b1 = ldA(cb, 1, 1);
      bf16x8 c0 = ldA(cb, 2, 0), c1 = ldA(cb, 2, 1);
      BAR();
      if (hf == 0) { stA(1, t1, 2); stA(1, t1, 3); } else { stA(0, pf0, 2); stA(0, pf0, 3); }
      __builtin_amdgcn_s_setprio(1);
      #pragma unroll
      for (int nf = 0; nf < 4; ++nf) {
        acc[1][nf] = __builtin_amdgcn_mfma_f32_16x16x32_bf16(b0, breg[nf][0], acc[1][nf], 0, 0, 0);
        acc[1][nf] = __builtin_amdgcn_mfma_f32_16x16x32_bf16(b1, breg[nf][1], acc[1][nf], 0, 0, 0);
        acc[2][nf] = __builtin_amdgcn_mfma_f32_16x16x32_bf16(c0, breg[nf][0], acc[2][nf], 0, 0, 0);
        acc[2][nf] = __builtin_amdgcn_mfma_f32_16x16x32_bf16(c1, breg[nf][1], acc[2][nf], 0, 0, 0);
      }
      __builtin_amdgcn_s_setprio(0);
      a0 = ldA(cb, 3, 0); a1 = ldA(cb, 3, 1);
      BAR();
      if (hf == 0) { stB(0, pf0, 0); stB(0, pf0, 1); } else { stB(1, pf1, 0); stB(1, pf1, 1); }
      __builtin_amdgcn_s_setprio(1);
      #pragma unroll
      for (int nf = 0; nf < 4; ++nf) {
        acc[3][nf] = __builtin_amdgcn_mfma_f32_16x16x32_bf16(a0, breg[nf][0], acc[3][nf], 0, 0, 0);
        acc[3][nf] = __builtin_amdgcn_mfma_f32_16x16x32_bf16(a1, breg[nf][1], acc[3][nf], 0, 0, 0);
      }
      __builtin_amdgcn_s_setprio(0);
      asm volatile("s_waitcnt vmcnt(2)" ::: "memory");
      BAR();
    }
  }
  asm volatile("s_waitcnt vmcnt(0)" ::: "memory");

  #pragma unroll
  for (int mf = 0; mf < 4; ++mf) {
    #pragma unroll
    for (int nf = 0; nf < 4; ++nf) {
      #pragma unroll
      for (int e = 0; e < 4; ++e) {
        int r = row0 + wm * 64 + mf * 16 + (lane >> 4) * 4 + e;
        int c = col0 + wn * 64 + nf * 16 + (lane & 15);
        C[(size_t)r * N + c] = acc[mf][nf][e] + bias[c];
      }
    }
  }
}

// ---------------------------------------------------------------- attn staging helpers
static __device__ __forceinline__ void stage_k_tile(
    const u16* __restrict__ QK, int b, int h, int j0, u16* Kbuf, int tid, int wid)
{
  #pragma unroll
  for (int i = 0; i < 4; i++) {
    int c = i * 256 + tid;
    int r = c >> 4, ob = (c & 15) * 16;
    int cb = ob ^ ((r & 7) << 4);
    const u16* g = QK + (size_t)(b*2048 + j0 + r) * 4096 + 2048 + h*128 + (cb >> 1);
    gload_lds16(g, Kbuf + (i * 256 + wid * 64) * 8);
  }
}
static __device__ __forceinline__ void stage_v_tile(
    const u16* __restrict__ Vt, int b, int h, int j0, u16* Vbuf, int tid, int wid)
{
  #pragma unroll
  for (int i = 0; i < 4; i++) {
    int c = i * 256 + tid;
    int r = c >> 3, ob = (c & 7) * 16;
    int cb = ob ^ ((r & 7) << 4);
    const u16* g = Vt + (size_t)((b*16 + h) * 128 + r) * 2048 + j0 + (cb >> 1);
    gload_lds16(g, Vbuf + (i * 256 + wid * 64) * 8);
  }
}

// ---------------------------------------------------------------- causal flash attention, QBLK=128
// SWAPPED QK operands: A/B MFMA fragments share the same per-lane layout
// (row=lane&15, 8 k-contig at (lane>>4)*8), so mfma(kb, qa) gives S^T with
// q = lane&15 and j = (lane>>4)*4+e — each lane holds 4 CONSECUTIVE-j P values
// per quadrant. P store becomes 8 ds_write_b64/lane/iter (was 32 ds_write_b16).
// Content convention both sides: byte(i,j) = i*128 + ((2j) ^ ((i&7)<<4)).
// lrun collapses to [2] (indexed by q = lane&15); epilogue redistributes via
// 2 xor-shfl (g-reduce) + shfl to o's row layout. Fixed-bound softmax kept.
__global__ __launch_bounds__(256, 2) void attn(
    const u16* __restrict__ QK, const u16* __restrict__ Vt, u16* __restrict__ AO)
{
  const int flat = blockIdx.x;
  const int xcd = flat & 7;
  const int j   = flat >> 3;
  const int k   = j >> 1, odd = j & 1;
  int qt, inst;
  if (k < 16) { qt = odd ? 15 - k : k;      inst = odd ? 1 : 0; }
  else        { qt = odd ? k - 16 : 31 - k; inst = odd ? 3 : 2; }
  const int hb = xcd * 4 + inst;
  const int h = hb & 15, b = hb >> 4;
  const int tid = threadIdx.x, lane = tid & 63, wid = tid >> 6;

  __shared__ u16 Ks[2][64 * 128];
  __shared__ u16 Vs[2][128 * 64];
  __shared__ u16 Ps[4][32 * 64];

  const int l0 = qt * 128;
  const int ntile = 2 * qt + 2;

  bf16x8 qa[2][4];
  #pragma unroll
  for (int mt = 0; mt < 2; mt++) {
    const u16* qrow = QK + (size_t)(b*2048 + l0 + wid*32 + mt*16 + (lane & 15)) * 4096
                      + h*128 + (lane >> 4) * 8;
    #pragma unroll
    for (int ks = 0; ks < 4; ks++) qa[mt][ks] = *(const bf16x8*)(qrow + ks * 32);
  }

  f32x4 o[2][8] = {};
  float lrun[2] = {0.f, 0.f};

  stage_v_tile(Vt, b, h, 0, Vs[0], tid, wid);
  stage_k_tile(QK, b, h, 0, Ks[0], tid, wid);
  int cur = 0;

  for (int t = 0; t < ntile; t++) {
    const int j0 = t * 64;
    if (t + 1 < ntile) {
      stage_v_tile(Vt, b, h, (t + 1) * 64, Vs[cur ^ 1], tid, wid);
      stage_k_tile(QK, b, h, (t + 1) * 64, Ks[cur ^ 1], tid, wid);
      asm volatile("s_waitcnt vmcnt(8)" ::: "memory");
    } else {
      asm volatile("s_waitcnt vmcnt(0)" ::: "memory");
    }
    __builtin_amdgcn_s_barrier();
    asm volatile("" ::: "memory");

    const bool skip = (t == ntile - 1) && (wid < 2);
    if (!skip) {
      // ---- S^T = K Q^T per wave: s[mt][nt] holds S[j=j0+nt*16+(g*4+e)][q=l0+wid*32+mt*16+(lane&15)]
      f32x4 s[2][4] = {};
      const char* Kc = (const char*)Ks[cur];
      __builtin_amdgcn_s_setprio(1);
      #pragma unroll
      for (int nt = 0; nt < 4; nt++) {
        #pragma unroll
        for (int ks = 0; ks < 4; ks++) {
          int r = nt * 16 + (lane & 15);
          int cb = ks * 64 + (lane >> 4) * 16;
          bf16x8 kb = *(const bf16x8*)(Kc + r * 256 + (cb ^ ((lane & 7) << 4)));
          s[0][nt] = __builtin_amdgcn_mfma_f32_16x16x32_bf16(kb, qa[0][ks], s[0][nt], 0, 0, 0);
          s[1][nt] = __builtin_amdgcn_mfma_f32_16x16x32_bf16(kb, qa[1][ks], s[1][nt], 0, 0, 0);
        }
      }
      __builtin_amdgcn_s_setprio(0);

      // ---- causal mask (last two tiles only); q = lane&15 slot, j = (lane>>4)*4+e
      if (t >= ntile - 2) {
        #pragma unroll
        for (int mt = 0; mt < 2; mt++) {
          #pragma unroll
          for (int nt = 0; nt < 4; nt++) {
            #pragma unroll
            for (int e = 0; e < 4; e++) {
              int qg = l0 + wid * 32 + mt * 16 + (lane & 15);
              int jg = j0 + nt * 16 + (lane >> 4) * 4 + e;
              if (jg > qg) s[mt][nt][e] = -1e30f;
            }
          }
        }
      }

      // ---- P = exp2(S); packed b64 store (4 consecutive j per lane)
      char* PsW = (char*)Ps[wid];
      #pragma unroll
      for (int mt = 0; mt < 2; mt++) {
        const int i_ = mt * 16 + (lane & 15);
        #pragma unroll
        for (int nt = 0; nt < 4; nt++) {
          u16x4 pk;
          #pragma unroll
          for (int e = 0; e < 4; e++) {
            float p = exp2f(s[mt][nt][e]);
            lrun[mt] += p;
            pk[e] = f2bf_trunc(p);
          }
          int ob = (nt * 32 + (lane >> 4) * 8) ^ ((i_ & 7) << 4);
          *(u16x4*)(PsW + i_ * 128 + ob) = pk;
        }
      }

      // ---- O += P V (unchanged read path: byte(i,j) = i*128 + (2j ^ ((i&7)<<4)))
      const char* Vc = (const char*)Vs[cur];
      __builtin_amdgcn_s_setprio(1);
      #pragma unroll
      for (int ks = 0; ks < 2; ks++) {
        int jb = ks * 64 + (lane >> 4) * 16;
        bf16x8 pa[2];
        #pragma unroll
        for (int mt = 0; mt < 2; mt++) {
          int ir = mt * 16 + (lane & 15);
          pa[mt] = *(const bf16x8*)(PsW + ir * 128 + (jb ^ ((ir & 7) << 4)));
        }
        #pragma unroll
        for (int dt = 0; dt < 8; dt++) {
          int dr = dt * 16 + (lane & 15);
          bf16x8 vb = *(const bf16x8*)(Vc + dr * 128 + (jb ^ ((lane & 7) << 4)));
          o[0][dt] = __builtin_amdgcn_mfma_f32_16x16x32_bf16(pa[0], vb, o[0][dt], 0, 0, 0);
          o[1][dt] = __builtin_amdgcn_mfma_f32_16x16x32_bf16(pa[1], vb, o[1][dt], 0, 0, 0);
        }
      }
      __builtin_amdgcn_s_setprio(0);
    }

    asm volatile("s_waitcnt lgkmcnt(0)" ::: "memory");
    __builtin_amdgcn_s_barrier();
    asm volatile("" ::: "memory");
    cur ^= 1;
  }

  // ---- epilogue: finish row sums (reduce across g-groups), redistribute to o layout
  #pragma unroll
  for (int mt = 0; mt < 2; mt++) {
    float l = lrun[mt];
    l += __shfl_xor(l, 16);
    l += __shfl_xor(l, 32);
    // lanes {q, q+16, q+32, q+48} now hold the total for q = mt*16 + (lane&15)
    #pragma unroll
    for (int e = 0; e < 4; e++) {
      float le = __shfl(l, (lane >> 4) * 4 + e);   // total for q-slot (lane>>4)*4+e (lanes 0-15 hold all)
      float inv = 1.0f / le;
      int rglob = b * 2048 + l0 + wid * 32 + mt * 16 + (lane >> 4) * 4 + e;
      #pragma unroll
      for (int dt = 0; dt < 8; dt++)
        AO[(size_t)rglob * 2048 + h * 128 + dt * 16 + (lane & 15)] = f2bf(o[mt][dt][e] * inv);
    }
  }
}

// ---------------------------------------------------------------- launch
extern "C" void kernel_launch(void* const* d_in, const int* in_sizes, int n_in,
                              void* d_out, int out_size, void* d_ws, size_t ws_size,
                              hipStream_t stream)
{
  const float* x  = (const float*)d_in[0];
  const float* Wq = (const float*)d_in[1];
  const float* Wk = (const float*)d_in[2];
  const float* Wv = (const float*)d_in[3];
  const float* Wo = (const float*)d_in[4];
  const float* bo = (const float*)d_in[5];

  char* ws = (char*)d_ws;
  u16* xb   = (u16*)(ws);
  u16* Wcat = (u16*)(ws + 16777216);
  u16* Wob  = (u16*)(ws + 16777216 + 25165824);
  u16* QK   = (u16*)(ws + 16777216 + 25165824 + 8388608);
  u16* Vt   = (u16*)(ws + 16777216 + 25165824 + 8388608 + 33554432);
  u16* AO   = xb;

  cast_all<<<dim3(2048), dim3(256), 0, stream>>>(x, Wq, Wk, Wv, Wo, xb, Wcat, Wob);
  gemm_qkv<<<dim3(32, 24), dim3(512), 0, stream>>>(xb, Wcat, QK, Vt, 2048);
  attn<<<dim3(512), dim3(256), 0, stream>>>(QK, Vt, AO);
  gemm_ao<<<dim3(16, 16), dim3(512), 0, stream>>>(AO, Wob, (float*)d_out, bo, 4096, 2048, 2048);
}